// Round 10
// baseline (127.052 us; speedup 1.0000x reference)
//
#include <hip/hip_runtime.h>
#include <hip/hip_bf16.h>

// NodeAggregator forward, round 10.
// STE => forward output == degree-normalized pooled; top-k dead.
// r9 structure; adj fixed: BK 32->64 (kills 4-way bank conflict: GR=8 full row&7
// spread; halves barrier count; doubles in-flight staged bytes), BN=128 + nh split
// (dup adj read L3-absorbed), A raw-f32 in LDS (cvt at frag read), 3-buf counted
// vmcnt, 72KB -> 2 blk/CU, grid 1024.

typedef float f32x4 __attribute__((ext_vector_type(4)));
typedef __bf16 bf16x8 __attribute__((ext_vector_type(8)));

#define VMCNT(n) asm volatile("s_waitcnt vmcnt(" #n ")" ::: "memory")
#define LGKM0    asm volatile("s_waitcnt lgkmcnt(0)" ::: "memory")
#define SCHEDB   __builtin_amdgcn_sched_barrier(0)
#define BARRIER                                        \
  do {                                                 \
    LGKM0;                                             \
    __builtin_amdgcn_s_barrier();                      \
    asm volatile("" ::: "memory");                     \
    SCHEDB;                                            \
  } while (0)

__device__ __forceinline__ void async_load16(const void* g, void* l) {
  __builtin_amdgcn_global_load_lds((const __attribute__((address_space(1))) void*)g,
                                   (__attribute__((address_space(3))) void*)l, 16, 0, 0);
}
__device__ __forceinline__ unsigned short f2bf(float f) {
  return __builtin_bit_cast(unsigned short, (__bf16)f);
}
__device__ __forceinline__ ushort4 f4_to_bf4(float4 v) {
  ushort4 u; u.x = f2bf(v.x); u.y = f2bf(v.y); u.z = f2bf(v.z); u.w = f2bf(v.w); return u;
}

// T2 swizzle on the SOURCE granule (rule #21); LDS stays linear for gloadlds.
template <int ROWS, int BK, int NT>
__device__ __forceinline__ void stage_bf16(const __bf16* __restrict__ src, long long ld,
                                           __bf16* lds, int t) {
  constexpr int GR = BK / 8;
  constexpr int N = ROWS * GR / NT;
  static_assert(N >= 1, "stage too small");
#pragma unroll
  for (int c = 0; c < N; ++c) {
    const int idx = c * NT + t;
    const int row = idx / GR;
    const int g = idx % GR;
    const int gs = g ^ (row & (GR - 1) & 7);
    async_load16(src + (long long)row * ld + gs * 8, lds + idx * 8);
  }
}
template <int BK>
__device__ __forceinline__ bf16x8 frag(const __bf16* lds, int row, int kq) {
  constexpr int GR = BK / 8;
  const int g = kq ^ (row & (GR - 1) & 7);
  return *(const bf16x8*)(lds + row * BK + g * 8);
}

// ---------------- prep: x [8,2048,512] f32 -> xbT [8,512,2048] bf16; W1T; W2T ------
__global__ __launch_bounds__(256) void prep_k(const float* __restrict__ x,
                                              const float* __restrict__ W1,
                                              const float* __restrict__ W2,
                                              __bf16* __restrict__ xbT,
                                              __bf16* __restrict__ W1T,
                                              __bf16* __restrict__ W2T) {
  __shared__ float tile[64][65];
  const int tr = threadIdx.x >> 6, tc = threadIdx.x & 63;
  const int bid = blockIdx.x;
  const float* in; __bf16* out; int r0, c0, C, R;
  if (bid < 2048) {
    const int fb = bid >> 8, rest = bid & 255;
    const int nb = rest >> 3, b = rest & 7;
    in = x + (long long)b * 1048576; out = xbT + (long long)b * 1048576;
    r0 = nb * 64; c0 = fb * 64; R = 2048; C = 512;
  } else if (bid < 2080) {
    const int w = bid - 2048;
    in = W1; out = W1T; r0 = (w >> 2) * 64; c0 = (w & 3) * 64; R = 512; C = 256;
  } else {
    const int w = bid - 2080;
    in = W2; out = W2T; r0 = (w >> 2) * 64; c0 = (w & 3) * 64; R = 256; C = 256;
  }
#pragma unroll
  for (int i = 0; i < 16; ++i)
    tile[tr + i * 4][tc] = in[(long long)(r0 + tr + i * 4) * C + c0 + tc];
  __syncthreads();
#pragma unroll
  for (int i = 0; i < 16; ++i)
    out[(long long)(c0 + tr + i * 4) * R + r0 + tc] = (__bf16)tile[tc][tr + i * 4];
}

// ---------------- fused assign (unchanged, verified since r4) ----------------------
__device__ __forceinline__ void asg_compute(const __bf16* __restrict__ Abuf,
                                            const __bf16* __restrict__ Bbuf,
                                            f32x4 (&acc)[2][4], int wn, int l15, int l4) {
  bf16x8 af[2], bf[4];
#pragma unroll
  for (int i = 0; i < 2; ++i) af[i] = frag<32>(Abuf, i * 16 + l15, l4);
#pragma unroll
  for (int j = 0; j < 4; ++j) bf[j] = frag<32>(Bbuf, wn + j * 16 + l15, l4);
  __builtin_amdgcn_s_setprio(1);
#pragma unroll
  for (int i = 0; i < 2; ++i)
#pragma unroll
    for (int j = 0; j < 4; ++j)
      acc[i][j] = __builtin_amdgcn_mfma_f32_16x16x32_bf16(af[i], bf[j], acc[i][j], 0, 0, 0);
  __builtin_amdgcn_s_setprio(0);
}

__global__ __launch_bounds__(256) void assign_fused_k(
    const float* __restrict__ x, const __bf16* __restrict__ W1T,
    const __bf16* __restrict__ W2T, const float* __restrict__ b1,
    const float* __restrict__ b2, const float* __restrict__ mask,
    __bf16* __restrict__ ST) {
  __shared__ alignas(16) __bf16 Ax[2][32 * 32];
  __shared__ alignas(16) __bf16 Bw[2][256 * 32];
  __shared__ alignas(16) __bf16 hl[32 * 264];
  __shared__ float red[2][4][32];

  const int t = threadIdx.x;
  const int lane = t & 63, wave = t >> 6;
  const int l15 = lane & 15, l4 = lane >> 4;
  const int wn = wave * 64;
  const long long row0 = (long long)blockIdx.x * 32;
  const float* Xb = x + row0 * 512;

  const int arow = t >> 3, afq = t & 7;
  const int ag = afq >> 1;
  const int aoff = arow * 32 + ((ag ^ (arow & 3)) * 8) + (afq & 1) * 4;

  auto ldx = [&](int tile) -> float4 {
    return *(const float4*)(Xb + (long long)arow * 512 + tile * 32 + afq * 4);
  };
  auto sta = [&](__bf16* dst, float4 v) { *(ushort4*)&dst[aoff] = f4_to_bf4(v); };

  f32x4 acc[2][4] = {};

  float4 xA = ldx(0);
  SCHEDB;
  stage_bf16<256, 32, 256>(W1T, 512, Bw[0], t);
  SCHEDB;
  VMCNT(4); SCHEDB;
  sta(Ax[0], xA);
  float4 xB = ldx(1);
  SCHEDB;
  VMCNT(1); SCHEDB;
  BARRIER;

#pragma unroll 1
  for (int tt = 0; tt < 14; tt += 2) {
    stage_bf16<256, 32, 256>(W1T + (tt + 1) * 32, 512, Bw[1], t);
    SCHEDB;
    xA = ldx(tt + 2);
    SCHEDB;
    asg_compute(Ax[0], Bw[0], acc, wn, l15, l4);
    VMCNT(5); SCHEDB;
    sta(Ax[1], xB);
    VMCNT(1); SCHEDB;
    BARRIER;
    stage_bf16<256, 32, 256>(W1T + (tt + 2) * 32, 512, Bw[0], t);
    SCHEDB;
    xB = ldx(tt + 3);
    SCHEDB;
    asg_compute(Ax[1], Bw[1], acc, wn, l15, l4);
    VMCNT(5); SCHEDB;
    sta(Ax[0], xA);
    VMCNT(1); SCHEDB;
    BARRIER;
  }
  stage_bf16<256, 32, 256>(W1T + 15 * 32, 512, Bw[1], t);
  SCHEDB;
  asg_compute(Ax[0], Bw[0], acc, wn, l15, l4);
  VMCNT(4); SCHEDB;
  sta(Ax[1], xB);
  VMCNT(0); SCHEDB;
  BARRIER;
  asg_compute(Ax[1], Bw[1], acc, wn, l15, l4);

  stage_bf16<256, 32, 256>(W2T, 256, Bw[0], t);
  SCHEDB;
#pragma unroll
  for (int j = 0; j < 4; ++j) {
    const int col = wn + j * 16 + l15;
    const float bv = b1[col];
#pragma unroll
    for (int i = 0; i < 2; ++i)
#pragma unroll
      for (int r = 0; r < 4; ++r)
        hl[(i * 16 + l4 * 4 + r) * 264 + col] = (__bf16)fmaxf(acc[i][j][r] + bv, 0.f);
  }
  VMCNT(0); SCHEDB;
  BARRIER;

  f32x4 acc2[2][4] = {};
#pragma unroll 1
  for (int tt = 0; tt < 8; ++tt) {
    if (tt < 7) stage_bf16<256, 32, 256>(W2T + (tt + 1) * 32, 256, Bw[(tt & 1) ^ 1], t);
    SCHEDB;
    const __bf16* Bc = Bw[tt & 1];
    bf16x8 af[2], bf[4];
#pragma unroll
    for (int i = 0; i < 2; ++i)
      af[i] = *(const bf16x8*)(&hl[(i * 16 + l15) * 264 + tt * 32 + l4 * 8]);
#pragma unroll
    for (int j = 0; j < 4; ++j) bf[j] = frag<32>(Bc, wn + j * 16 + l15, l4);
#pragma unroll
    for (int i = 0; i < 2; ++i)
#pragma unroll
      for (int j = 0; j < 4; ++j)
        acc2[i][j] = __builtin_amdgcn_mfma_f32_16x16x32_bf16(af[i], bf[j], acc2[i][j], 0, 0, 0);
    VMCNT(0); SCHEDB;
    BARRIER;
  }

  float mb[2][4], mx[2][4], sm[2][4];
#pragma unroll
  for (int i = 0; i < 2; ++i)
#pragma unroll
    for (int r = 0; r < 4; ++r) {
      mb[i][r] = -1e9f * (1.0f - mask[row0 + i * 16 + l4 * 4 + r]);
      mx[i][r] = -3.4e38f;
      sm[i][r] = 0.f;
    }
#pragma unroll
  for (int j = 0; j < 4; ++j) {
    const float bv = b2[wn + j * 16 + l15];
#pragma unroll
    for (int i = 0; i < 2; ++i)
#pragma unroll
      for (int r = 0; r < 4; ++r) {
        const float v = acc2[i][j][r] + bv + mb[i][r];
        acc2[i][j][r] = v;
        mx[i][r] = fmaxf(mx[i][r], v);
      }
  }
#pragma unroll
  for (int i = 0; i < 2; ++i)
#pragma unroll
    for (int r = 0; r < 4; ++r) {
      float m = mx[i][r];
      m = fmaxf(m, __shfl_xor(m, 1, 64)); m = fmaxf(m, __shfl_xor(m, 2, 64));
      m = fmaxf(m, __shfl_xor(m, 4, 64)); m = fmaxf(m, __shfl_xor(m, 8, 64));
      mx[i][r] = m;
    }
  if (l15 == 0)
#pragma unroll
    for (int i = 0; i < 2; ++i)
#pragma unroll
      for (int r = 0; r < 4; ++r) red[0][wave][i * 16 + l4 * 4 + r] = mx[i][r];
  __syncthreads();
#pragma unroll
  for (int i = 0; i < 2; ++i)
#pragma unroll
    for (int r = 0; r < 4; ++r) {
      const int rl = i * 16 + l4 * 4 + r;
      mx[i][r] = fmaxf(fmaxf(red[0][0][rl], red[0][1][rl]),
                       fmaxf(red[0][2][rl], red[0][3][rl]));
    }
#pragma unroll
  for (int j = 0; j < 4; ++j)
#pragma unroll
    for (int i = 0; i < 2; ++i)
#pragma unroll
      for (int r = 0; r < 4; ++r) {
        const float e = __expf(acc2[i][j][r] - mx[i][r]);
        acc2[i][j][r] = e;
        sm[i][r] += e;
      }
#pragma unroll
  for (int i = 0; i < 2; ++i)
#pragma unroll
    for (int r = 0; r < 4; ++r) {
      float s = sm[i][r];
      s += __shfl_xor(s, 1, 64); s += __shfl_xor(s, 2, 64);
      s += __shfl_xor(s, 4, 64); s += __shfl_xor(s, 8, 64);
      sm[i][r] = s;
    }
  if (l15 == 0)
#pragma unroll
    for (int i = 0; i < 2; ++i)
#pragma unroll
      for (int r = 0; r < 4; ++r) red[1][wave][i * 16 + l4 * 4 + r] = sm[i][r];
  __syncthreads();
  float inv[2][4];
#pragma unroll
  for (int i = 0; i < 2; ++i)
#pragma unroll
    for (int r = 0; r < 4; ++r) {
      const int rl = i * 16 + l4 * 4 + r;
      inv[i][r] = 1.0f / (red[1][0][rl] + red[1][1][rl] + red[1][2][rl] + red[1][3][rl]);
    }
  const long long bb = row0 >> 11;
  const long long n0 = row0 & 2047;
  __bf16* Sb = ST + bb * 524288;
#pragma unroll
  for (int j = 0; j < 4; ++j) {
    const int col = wn + j * 16 + l15;
#pragma unroll
    for (int i = 0; i < 2; ++i) {
      ushort4 u;
      u.x = f2bf(acc2[i][j][0] * inv[i][0]);
      u.y = f2bf(acc2[i][j][1] * inv[i][1]);
      u.z = f2bf(acc2[i][j][2] * inv[i][2]);
      u.w = f2bf(acc2[i][j][3] * inv[i][3]);
      *(ushort4*)(Sb + (long long)col * 2048 + n0 + i * 16 + l4 * 4) = u;
    }
  }
}

// ---------------- G3: midT = (adj @ S)^T; BK=64 conflict-free 3-buf ----------------
// BM=32 (adj rows), BN=128 (nh half), BK=64; 72KB -> 2 blk/CU; grid 1024; 32 steps.
// A staged as raw f32 (row = 256B = 16 granules, row&7 spread -> 2-way max = free);
// B BK=64 (GR=8 full spread -> conflict-free, matches proven feat profile).
__global__ __launch_bounds__(256) void gemm_adj_k(const float* __restrict__ adj,
                                                  const __bf16* __restrict__ ST,
                                                  __bf16* __restrict__ midT) {
  __shared__ alignas(16) __bf16 As[3][32 * 128];  // 8 KB/buf (f32 payload)
  __shared__ alignas(16) __bf16 Bs[3][128 * 64];  // 16 KB/buf
  const int t = threadIdx.x;
  const int lane = t & 63, wave = t >> 6;
  const int l15 = lane & 15, l4 = lane >> 4;
  const int wn = wave * 32;
  const int id = blockIdx.x;   // 1024: batch=id&7 (XCD pin), nh=bit3, slab=id>>4
  const int bz = id & 7;
  const int nh = (id >> 3) & 1;
  const long long r0 = (long long)(id >> 4) * 32;
  // A viewed as bf16-units: row stride 4096 units, K-step stride 128 units (=64 f32)
  const __bf16* Abh = (const __bf16*)(adj + (long long)bz * 4194304 + r0 * 2048);
  const __bf16* Bb = ST + (long long)bz * 524288 + (long long)nh * 128 * 2048;

  auto stage = [&](int s, int buf) {  // 2 A-gloadlds + 4 B-gloadlds per thread
    stage_bf16<32, 128, 256>(Abh + s * 128, 4096, (__bf16*)As + buf * 4096, t);
    stage_bf16<128, 64, 256>(Bb + s * 64, 2048, (__bf16*)Bs + buf * 8192, t);
  };
  auto afrag = [&](const __bf16* Ac, int row, int ks) {
    // 8 f32 at f32-col ks*32 + l4*8 -> granules ks*8 + l4*2, +1 (XOR row&7 in frag)
    f32x4 lo = __builtin_bit_cast(f32x4, frag<128>(Ac, row, ks * 8 + l4 * 2));
    f32x4 hi = __builtin_bit_cast(f32x4, frag<128>(Ac, row, ks * 8 + l4 * 2 + 1));
    bf16x8 r;
    r[0] = (__bf16)lo[0]; r[1] = (__bf16)lo[1]; r[2] = (__bf16)lo[2]; r[3] = (__bf16)lo[3];
    r[4] = (__bf16)hi[0]; r[5] = (__bf16)hi[1]; r[6] = (__bf16)hi[2]; r[7] = (__bf16)hi[3];
    return r;
  };
  f32x4 acc[2][2] = {};
  auto cmp = [&](int buf) {
    const __bf16* Ac = (const __bf16*)As + buf * 4096;
    const __bf16* Bc = (const __bf16*)Bs + buf * 8192;
#pragma unroll
    for (int ks = 0; ks < 2; ++ks) {
      bf16x8 af[2], bf[2];
#pragma unroll
      for (int i = 0; i < 2; ++i) af[i] = afrag(Ac, i * 16 + l15, ks);
#pragma unroll
      for (int j = 0; j < 2; ++j) bf[j] = frag<64>(Bc, wn + j * 16 + l15, ks * 4 + l4);
      __builtin_amdgcn_s_setprio(1);
#pragma unroll
      for (int i = 0; i < 2; ++i)
#pragma unroll
        for (int j = 0; j < 2; ++j)
          acc[i][j] = __builtin_amdgcn_mfma_f32_16x16x32_bf16(af[i], bf[j], acc[i][j], 0, 0, 0);
      __builtin_amdgcn_s_setprio(0);
    }
  };

  stage(0, 0);
  SCHEDB;
  stage(1, 1);
  SCHEDB;
  VMCNT(6); SCHEDB;  // tile0 (6 loads) done; tile1's 6 in flight
  BARRIER;

  int cur = 0, stg = 2;
#pragma unroll 1
  for (int tt = 0; tt < 30; ++tt) {  // K=2048, BK=64 -> 32 tiles
    stage(tt + 2, stg);
    SCHEDB;                          // [t+1:6, t+2:6]
    cmp(cur);
    VMCNT(6); SCHEDB;                // retire t+1; t+2 stays in flight
    BARRIER;
    cur = (cur == 2) ? 0 : cur + 1;
    stg = (stg == 2) ? 0 : stg + 1;
  }
  cmp(cur);                          // tile 30
  VMCNT(0); SCHEDB;                  // tile 31 done
  BARRIER;
  cur = (cur == 2) ? 0 : cur + 1;
  cmp(cur);                          // tile 31

  __bf16* Cb = midT + (long long)bz * 524288;
#pragma unroll
  for (int j = 0; j < 2; ++j) {
    const int l = nh * 128 + wn + j * 16 + l15;
#pragma unroll
    for (int i = 0; i < 2; ++i) {
      ushort4 u;
      u.x = f2bf(acc[i][j][0]); u.y = f2bf(acc[i][j][1]);
      u.z = f2bf(acc[i][j][2]); u.w = f2bf(acc[i][j][3]);
      *(ushort4*)(Cb + (long long)l * 2048 + r0 + i * 16 + l4 * 4) = u;
    }
  }
}

// ---------------- G5: pfeat = ST @ xbT^T; triple-buffer counted-vmcnt (proven) -----
__global__ __launch_bounds__(256) void gemm_feat_k(const __bf16* __restrict__ ST,
                                                   const __bf16* __restrict__ xbT,
                                                   float* __restrict__ pfeat) {
  __shared__ alignas(16) __bf16 As[3][32 * 64];  // 12 KB
  __shared__ alignas(16) __bf16 Bs[3][64 * 64];  // 24 KB
  const int t = threadIdx.x;
  const int lane = t & 63, wave = t >> 6;
  const int l15 = lane & 15, l4 = lane >> 4;
  const int wn = wave * 16;
  const int id = blockIdx.x;   // 512: b=id&7 (XCD pin), kblk, fblk
  const int b = id & 7, j7 = id >> 3;
  const int kblk = j7 & 7, fblk = j7 >> 3;
  const __bf16* Ab = ST + (long long)b * 524288 + (long long)kblk * 32 * 2048;
  const __bf16* Bb = xbT + (long long)b * 1048576 + (long long)fblk * 64 * 2048;

  auto stage = [&](int s, int buf) {  // 3 gloadlds/thread
    stage_bf16<32, 64, 256>(Ab + s * 64, 2048, (__bf16*)As + buf * 2048, t);
    stage_bf16<64, 64, 256>(Bb + s * 64, 2048, (__bf16*)Bs + buf * 4096, t);
  };
  auto cmp = [&](int buf, f32x4 (&acc)[2]) {
    const __bf16* Ac = (const __bf16*)As + buf * 2048;
    const __bf16* Bc = (const __bf16*)Bs + buf * 4096;
#pragma unroll
    for (int ks = 0; ks < 2; ++ks) {
      bf16x8 af[2], bf;
#pragma unroll
      for (int i = 0; i < 2; ++i) af[i] = frag<64>(Ac, i * 16 + l15, ks * 4 + l4);
      bf = frag<64>(Bc, wn + l15, ks * 4 + l4);
#pragma unroll
      for (int i = 0; i < 2; ++i)
        acc[i] = __builtin_amdgcn_mfma_f32_16x16x32_bf16(af[i], bf, acc[i], 0, 0, 0);
    }
  };

  f32x4 acc[2] = {};
  stage(0, 0);
  SCHEDB;
  stage(1, 1);
  SCHEDB;
  VMCNT(3); SCHEDB;
  BARRIER;

  int cur = 0, stg = 2;
#pragma unroll 1
  for (int tt = 0; tt < 30; ++tt) {
    stage(tt + 2, stg);
    SCHEDB;
    cmp(cur, acc);
    VMCNT(3); SCHEDB;
    BARRIER;
    cur = (cur == 2) ? 0 : cur + 1;
    stg = (stg == 2) ? 0 : stg + 1;
  }
  cmp(cur, acc);
  VMCNT(0); SCHEDB;
  BARRIER;
  cur = (cur == 2) ? 0 : cur + 1;
  cmp(cur, acc);

  float* out = pfeat + (long long)b * 131072;
#pragma unroll
  for (int i = 0; i < 2; ++i)
#pragma unroll
    for (int r = 0; r < 4; ++r)
      out[(long long)(kblk * 32 + i * 16 + l4 * 4 + r) * 512 + fblk * 64 + wn + l15] =
          acc[i][r];
}

// ---------------- G4: pooled = ST @ midT^T; triple-buffer counted-vmcnt (proven) ---
__global__ __launch_bounds__(256) void gemm_pool_k(const __bf16* __restrict__ ST,
                                                   const __bf16* __restrict__ midT,
                                                   float* __restrict__ pooled) {
  __shared__ alignas(16) __bf16 As[3][32 * 64];
  __shared__ alignas(16) __bf16 Bs[3][32 * 64];
  const int t = threadIdx.x;
  const int lane = t & 63, wave = t >> 6;
  const int l15 = lane & 15, l4 = lane >> 4;
  const int wm = (wave >> 1) * 16, wn = (wave & 1) * 16;
  const int id = blockIdx.x;
  const int b = id & 7, j7 = id >> 3;
  const int kblk = j7 & 7, lblk = j7 >> 3;
  const __bf16* Ab = ST + (long long)b * 524288 + (long long)kblk * 32 * 2048;
  const __bf16* Bb = midT + (long long)b * 524288 + (long long)lblk * 32 * 2048;

  auto stage = [&](int s, int buf) {
    stage_bf16<32, 64, 256>(Ab + s * 64, 2048, (__bf16*)As + buf * 2048, t);
    stage_bf16<32, 64, 256>(Bb + s * 64, 2048, (__bf16*)Bs + buf * 2048, t);
  };
  auto cmp = [&](int buf, f32x4& acc) {
    const __bf16* Ac = (const __bf16*)As + buf * 2048;
    const __bf16* Bc = (const __bf16*)Bs + buf * 2048;
#pragma unroll
    for (int ks = 0; ks < 2; ++ks) {
      bf16x8 af = frag<64>(Ac, wm + l15, ks * 4 + l4);
      bf16x8 bf = frag<64>(Bc, wn + l15, ks * 4 + l4);
      acc = __builtin_amdgcn_mfma_f32_16x16x32_bf16(af, bf, acc, 0, 0, 0);
    }
  };

  f32x4 acc = {};
  stage(0, 0);
  SCHEDB;
  stage(1, 1);
  SCHEDB;
  VMCNT(2); SCHEDB;
  BARRIER;

  int cur = 0, stg = 2;
#pragma unroll 1
  for (int tt = 0; tt < 30; ++tt) {
    stage(tt + 2, stg);
    SCHEDB;
    cmp(cur, acc);
    VMCNT(2); SCHEDB;
    BARRIER;
    cur = (cur == 2) ? 0 : cur + 1;
    stg = (stg == 2) ? 0 : stg + 1;
  }
  cmp(cur, acc);
  VMCNT(0); SCHEDB;
  BARRIER;
  cur = (cur == 2) ? 0 : cur + 1;
  cmp(cur, acc);

  float* out = pooled + (long long)b * 65536;
#pragma unroll
  for (int r = 0; r < 4; ++r)
    out[(long long)(kblk * 32 + wm + l4 * 4 + r) * 256 + lblk * 32 + wn + l15] = acc[r];
}

// ---------------- rowsum -> dinv; finalize ----------------
__global__ __launch_bounds__(256) void rowsum_k(const float* __restrict__ pooled,
                                                float* __restrict__ dinv) {
  const int gr = blockIdx.x * 4 + (threadIdx.x >> 6);
  const int lane = threadIdx.x & 63;
  const float* p = pooled + (long long)gr * 256;
  float s = p[lane] + p[lane + 64] + p[lane + 128] + p[lane + 192];
#pragma unroll
  for (int o = 32; o > 0; o >>= 1) s += __shfl_xor(s, o, 64);
  if (lane == 0) dinv[gr] = rsqrtf(s + 1e-9f);
}

__global__ __launch_bounds__(256) void finalize_k(const float* __restrict__ pooled,
                                                  const float* __restrict__ dinv,
                                                  float* __restrict__ outAdj,
                                                  float* __restrict__ pmask) {
  const long long i = blockIdx.x * 256LL + threadIdx.x;
  const int c = (int)(i & 255);
  const int r = (int)((i >> 8) & 255);
  const int b = (int)(i >> 16);
  outAdj[i] = pooled[i] * dinv[b * 256 + r] * dinv[b * 256 + c];
  if (i < 2048) pmask[i] = 1.0f;
}

extern "C" void kernel_launch(void* const* d_in, const int* in_sizes, int n_in,
                              void* d_out, int out_size, void* d_ws, size_t ws_size,
                              hipStream_t stream) {
  (void)in_sizes; (void)n_in; (void)out_size; (void)ws_size;
  const float* x    = (const float*)d_in[0];  // [8,2048,512]
  const float* adj  = (const float*)d_in[1];  // [8,2048,2048]
  const float* mask = (const float*)d_in[2];  // [8,2048]
  const float* W1   = (const float*)d_in[3];  // [512,256]
  const float* b1   = (const float*)d_in[4];  // [256]
  const float* W2   = (const float*)d_in[5];  // [256,256]
  const float* b2   = (const float*)d_in[6];  // [256]

  char* ws = (char*)d_ws;  // total 36,052,992 B (~34.4 MiB)
  __bf16* ST     = (__bf16*)(ws + 0);          //  8,388,608  [8][256][2048]
  __bf16* midT   = (__bf16*)(ws + 8388608);    //  8,388,608  [8][256][2048]
  __bf16* xbT    = (__bf16*)(ws + 16777216);   // 16,777,216  [8][512][2048]
  float*  pooled = (float*)(ws + 33554432);    //  2,097,152  [8][256][256]
  float*  dinv   = (float*)(ws + 35651584);    //      8,192  [8][256]
  __bf16* W1T    = (__bf16*)(ws + 35659776);   //    262,144  [256][512]
  __bf16* W2T    = (__bf16*)(ws + 35921920);   //    131,072  [256][256]

  float* pfeat  = (float*)d_out;               // [8,256,512]
  float* outAdj = (float*)d_out + 1048576;     // [8,256,256]
  float* pmask  = (float*)d_out + 1572864;     // [8,256]

  prep_k<<<2096, 256, 0, stream>>>(x, W1, W2, xbT, W1T, W2T);
  assign_fused_k<<<512, 256, 0, stream>>>(x, W1T, W2T, b1, b2, mask, ST);
  gemm_feat_k<<<512, 256, 0, stream>>>(ST, xbT, pfeat);
  gemm_adj_k<<<1024, 256, 0, stream>>>(adj, ST, midT);
  gemm_pool_k<<<512, 256, 0, stream>>>(ST, midT, pooled);
  rowsum_k<<<512, 256, 0, stream>>>(pooled, dinv);
  finalize_k<<<2048, 256, 0, stream>>>(pooled, dinv, outAdj, pmask);
}

// Round 11
// 113.546 us; speedup vs baseline: 1.1189x; 1.1189x over previous
//
#include <hip/hip_runtime.h>
#include <hip/hip_bf16.h>

// NodeAggregator forward, round 11.
// STE => forward output == degree-normalized pooled; top-k dead.
// adj rebuilt from ONLY measured-0-conflict parts: A f32->reg->cvt->ds_write (r5),
// B gloadlds BK=64 3-buf frag<64> (feat), counted-vmcnt FIFO, BM=64 (halves B
// re-staging), 64KB LDS -> 2 blk/CU, grid 512. f32-in-LDS A abandoned (r9/r10:
// 6.3M/4.2M conflicts). Other kernels unchanged (proven).

typedef float f32x4 __attribute__((ext_vector_type(4)));
typedef __bf16 bf16x8 __attribute__((ext_vector_type(8)));

#define VMCNT(n) asm volatile("s_waitcnt vmcnt(" #n ")" ::: "memory")
#define LGKM0    asm volatile("s_waitcnt lgkmcnt(0)" ::: "memory")
#define SCHEDB   __builtin_amdgcn_sched_barrier(0)
#define BARRIER                                        \
  do {                                                 \
    LGKM0;                                             \
    __builtin_amdgcn_s_barrier();                      \
    asm volatile("" ::: "memory");                     \
    SCHEDB;                                            \
  } while (0)

__device__ __forceinline__ void async_load16(const void* g, void* l) {
  __builtin_amdgcn_global_load_lds((const __attribute__((address_space(1))) void*)g,
                                   (__attribute__((address_space(3))) void*)l, 16, 0, 0);
}
__device__ __forceinline__ unsigned short f2bf(float f) {
  return __builtin_bit_cast(unsigned short, (__bf16)f);
}
__device__ __forceinline__ ushort4 f4_to_bf4(float4 v) {
  ushort4 u; u.x = f2bf(v.x); u.y = f2bf(v.y); u.z = f2bf(v.z); u.w = f2bf(v.w); return u;
}

// T2 swizzle on the SOURCE granule (rule #21); LDS stays linear for gloadlds.
template <int ROWS, int BK, int NT>
__device__ __forceinline__ void stage_bf16(const __bf16* __restrict__ src, long long ld,
                                           __bf16* lds, int t) {
  constexpr int GR = BK / 8;
  constexpr int N = ROWS * GR / NT;
  static_assert(N >= 1, "stage too small");
#pragma unroll
  for (int c = 0; c < N; ++c) {
    const int idx = c * NT + t;
    const int row = idx / GR;
    const int g = idx % GR;
    const int gs = g ^ (row & (GR - 1) & 7);
    async_load16(src + (long long)row * ld + gs * 8, lds + idx * 8);
  }
}
template <int BK>
__device__ __forceinline__ bf16x8 frag(const __bf16* lds, int row, int kq) {
  constexpr int GR = BK / 8;
  const int g = kq ^ (row & (GR - 1) & 7);
  return *(const bf16x8*)(lds + row * BK + g * 8);
}

// ---------------- prep: x [8,2048,512] f32 -> xbT [8,512,2048] bf16; W1T; W2T ------
__global__ __launch_bounds__(256) void prep_k(const float* __restrict__ x,
                                              const float* __restrict__ W1,
                                              const float* __restrict__ W2,
                                              __bf16* __restrict__ xbT,
                                              __bf16* __restrict__ W1T,
                                              __bf16* __restrict__ W2T) {
  __shared__ float tile[64][65];
  const int tr = threadIdx.x >> 6, tc = threadIdx.x & 63;
  const int bid = blockIdx.x;
  const float* in; __bf16* out; int r0, c0, C, R;
  if (bid < 2048) {
    const int fb = bid >> 8, rest = bid & 255;
    const int nb = rest >> 3, b = rest & 7;
    in = x + (long long)b * 1048576; out = xbT + (long long)b * 1048576;
    r0 = nb * 64; c0 = fb * 64; R = 2048; C = 512;
  } else if (bid < 2080) {
    const int w = bid - 2048;
    in = W1; out = W1T; r0 = (w >> 2) * 64; c0 = (w & 3) * 64; R = 512; C = 256;
  } else {
    const int w = bid - 2080;
    in = W2; out = W2T; r0 = (w >> 2) * 64; c0 = (w & 3) * 64; R = 256; C = 256;
  }
#pragma unroll
  for (int i = 0; i < 16; ++i)
    tile[tr + i * 4][tc] = in[(long long)(r0 + tr + i * 4) * C + c0 + tc];
  __syncthreads();
#pragma unroll
  for (int i = 0; i < 16; ++i)
    out[(long long)(c0 + tr + i * 4) * R + r0 + tc] = (__bf16)tile[tc][tr + i * 4];
}

// ---------------- fused assign (unchanged, verified since r4) ----------------------
__device__ __forceinline__ void asg_compute(const __bf16* __restrict__ Abuf,
                                            const __bf16* __restrict__ Bbuf,
                                            f32x4 (&acc)[2][4], int wn, int l15, int l4) {
  bf16x8 af[2], bf[4];
#pragma unroll
  for (int i = 0; i < 2; ++i) af[i] = frag<32>(Abuf, i * 16 + l15, l4);
#pragma unroll
  for (int j = 0; j < 4; ++j) bf[j] = frag<32>(Bbuf, wn + j * 16 + l15, l4);
  __builtin_amdgcn_s_setprio(1);
#pragma unroll
  for (int i = 0; i < 2; ++i)
#pragma unroll
    for (int j = 0; j < 4; ++j)
      acc[i][j] = __builtin_amdgcn_mfma_f32_16x16x32_bf16(af[i], bf[j], acc[i][j], 0, 0, 0);
  __builtin_amdgcn_s_setprio(0);
}

__global__ __launch_bounds__(256) void assign_fused_k(
    const float* __restrict__ x, const __bf16* __restrict__ W1T,
    const __bf16* __restrict__ W2T, const float* __restrict__ b1,
    const float* __restrict__ b2, const float* __restrict__ mask,
    __bf16* __restrict__ ST) {
  __shared__ alignas(16) __bf16 Ax[2][32 * 32];
  __shared__ alignas(16) __bf16 Bw[2][256 * 32];
  __shared__ alignas(16) __bf16 hl[32 * 264];
  __shared__ float red[2][4][32];

  const int t = threadIdx.x;
  const int lane = t & 63, wave = t >> 6;
  const int l15 = lane & 15, l4 = lane >> 4;
  const int wn = wave * 64;
  const long long row0 = (long long)blockIdx.x * 32;
  const float* Xb = x + row0 * 512;

  const int arow = t >> 3, afq = t & 7;
  const int ag = afq >> 1;
  const int aoff = arow * 32 + ((ag ^ (arow & 3)) * 8) + (afq & 1) * 4;

  auto ldx = [&](int tile) -> float4 {
    return *(const float4*)(Xb + (long long)arow * 512 + tile * 32 + afq * 4);
  };
  auto sta = [&](__bf16* dst, float4 v) { *(ushort4*)&dst[aoff] = f4_to_bf4(v); };

  f32x4 acc[2][4] = {};

  float4 xA = ldx(0);
  SCHEDB;
  stage_bf16<256, 32, 256>(W1T, 512, Bw[0], t);
  SCHEDB;
  VMCNT(4); SCHEDB;
  sta(Ax[0], xA);
  float4 xB = ldx(1);
  SCHEDB;
  VMCNT(1); SCHEDB;
  BARRIER;

#pragma unroll 1
  for (int tt = 0; tt < 14; tt += 2) {
    stage_bf16<256, 32, 256>(W1T + (tt + 1) * 32, 512, Bw[1], t);
    SCHEDB;
    xA = ldx(tt + 2);
    SCHEDB;
    asg_compute(Ax[0], Bw[0], acc, wn, l15, l4);
    VMCNT(5); SCHEDB;
    sta(Ax[1], xB);
    VMCNT(1); SCHEDB;
    BARRIER;
    stage_bf16<256, 32, 256>(W1T + (tt + 2) * 32, 512, Bw[0], t);
    SCHEDB;
    xB = ldx(tt + 3);
    SCHEDB;
    asg_compute(Ax[1], Bw[1], acc, wn, l15, l4);
    VMCNT(5); SCHEDB;
    sta(Ax[0], xA);
    VMCNT(1); SCHEDB;
    BARRIER;
  }
  stage_bf16<256, 32, 256>(W1T + 15 * 32, 512, Bw[1], t);
  SCHEDB;
  asg_compute(Ax[0], Bw[0], acc, wn, l15, l4);
  VMCNT(4); SCHEDB;
  sta(Ax[1], xB);
  VMCNT(0); SCHEDB;
  BARRIER;
  asg_compute(Ax[1], Bw[1], acc, wn, l15, l4);

  stage_bf16<256, 32, 256>(W2T, 256, Bw[0], t);
  SCHEDB;
#pragma unroll
  for (int j = 0; j < 4; ++j) {
    const int col = wn + j * 16 + l15;
    const float bv = b1[col];
#pragma unroll
    for (int i = 0; i < 2; ++i)
#pragma unroll
      for (int r = 0; r < 4; ++r)
        hl[(i * 16 + l4 * 4 + r) * 264 + col] = (__bf16)fmaxf(acc[i][j][r] + bv, 0.f);
  }
  VMCNT(0); SCHEDB;
  BARRIER;

  f32x4 acc2[2][4] = {};
#pragma unroll 1
  for (int tt = 0; tt < 8; ++tt) {
    if (tt < 7) stage_bf16<256, 32, 256>(W2T + (tt + 1) * 32, 256, Bw[(tt & 1) ^ 1], t);
    SCHEDB;
    const __bf16* Bc = Bw[tt & 1];
    bf16x8 af[2], bf[4];
#pragma unroll
    for (int i = 0; i < 2; ++i)
      af[i] = *(const bf16x8*)(&hl[(i * 16 + l15) * 264 + tt * 32 + l4 * 8]);
#pragma unroll
    for (int j = 0; j < 4; ++j) bf[j] = frag<32>(Bc, wn + j * 16 + l15, l4);
#pragma unroll
    for (int i = 0; i < 2; ++i)
#pragma unroll
      for (int j = 0; j < 4; ++j)
        acc2[i][j] = __builtin_amdgcn_mfma_f32_16x16x32_bf16(af[i], bf[j], acc2[i][j], 0, 0, 0);
    VMCNT(0); SCHEDB;
    BARRIER;
  }

  float mb[2][4], mx[2][4], sm[2][4];
#pragma unroll
  for (int i = 0; i < 2; ++i)
#pragma unroll
    for (int r = 0; r < 4; ++r) {
      mb[i][r] = -1e9f * (1.0f - mask[row0 + i * 16 + l4 * 4 + r]);
      mx[i][r] = -3.4e38f;
      sm[i][r] = 0.f;
    }
#pragma unroll
  for (int j = 0; j < 4; ++j) {
    const float bv = b2[wn + j * 16 + l15];
#pragma unroll
    for (int i = 0; i < 2; ++i)
#pragma unroll
      for (int r = 0; r < 4; ++r) {
        const float v = acc2[i][j][r] + bv + mb[i][r];
        acc2[i][j][r] = v;
        mx[i][r] = fmaxf(mx[i][r], v);
      }
  }
#pragma unroll
  for (int i = 0; i < 2; ++i)
#pragma unroll
    for (int r = 0; r < 4; ++r) {
      float m = mx[i][r];
      m = fmaxf(m, __shfl_xor(m, 1, 64)); m = fmaxf(m, __shfl_xor(m, 2, 64));
      m = fmaxf(m, __shfl_xor(m, 4, 64)); m = fmaxf(m, __shfl_xor(m, 8, 64));
      mx[i][r] = m;
    }
  if (l15 == 0)
#pragma unroll
    for (int i = 0; i < 2; ++i)
#pragma unroll
      for (int r = 0; r < 4; ++r) red[0][wave][i * 16 + l4 * 4 + r] = mx[i][r];
  __syncthreads();
#pragma unroll
  for (int i = 0; i < 2; ++i)
#pragma unroll
    for (int r = 0; r < 4; ++r) {
      const int rl = i * 16 + l4 * 4 + r;
      mx[i][r] = fmaxf(fmaxf(red[0][0][rl], red[0][1][rl]),
                       fmaxf(red[0][2][rl], red[0][3][rl]));
    }
#pragma unroll
  for (int j = 0; j < 4; ++j)
#pragma unroll
    for (int i = 0; i < 2; ++i)
#pragma unroll
      for (int r = 0; r < 4; ++r) {
        const float e = __expf(acc2[i][j][r] - mx[i][r]);
        acc2[i][j][r] = e;
        sm[i][r] += e;
      }
#pragma unroll
  for (int i = 0; i < 2; ++i)
#pragma unroll
    for (int r = 0; r < 4; ++r) {
      float s = sm[i][r];
      s += __shfl_xor(s, 1, 64); s += __shfl_xor(s, 2, 64);
      s += __shfl_xor(s, 4, 64); s += __shfl_xor(s, 8, 64);
      sm[i][r] = s;
    }
  if (l15 == 0)
#pragma unroll
    for (int i = 0; i < 2; ++i)
#pragma unroll
      for (int r = 0; r < 4; ++r) red[1][wave][i * 16 + l4 * 4 + r] = sm[i][r];
  __syncthreads();
  float inv[2][4];
#pragma unroll
  for (int i = 0; i < 2; ++i)
#pragma unroll
    for (int r = 0; r < 4; ++r) {
      const int rl = i * 16 + l4 * 4 + r;
      inv[i][r] = 1.0f / (red[1][0][rl] + red[1][1][rl] + red[1][2][rl] + red[1][3][rl]);
    }
  const long long bb = row0 >> 11;
  const long long n0 = row0 & 2047;
  __bf16* Sb = ST + bb * 524288;
#pragma unroll
  for (int j = 0; j < 4; ++j) {
    const int col = wn + j * 16 + l15;
#pragma unroll
    for (int i = 0; i < 2; ++i) {
      ushort4 u;
      u.x = f2bf(acc2[i][j][0] * inv[i][0]);
      u.y = f2bf(acc2[i][j][1] * inv[i][1]);
      u.z = f2bf(acc2[i][j][2] * inv[i][2]);
      u.w = f2bf(acc2[i][j][3] * inv[i][3]);
      *(ushort4*)(Sb + (long long)col * 2048 + n0 + i * 16 + l4 * 4) = u;
    }
  }
}

// ---------------- G3: midT = (adj @ S)^T; proven-parts rebuild ---------------------
// BM=64 (adj rows), BN=128 (nh half), BK=64; grid 512 (slab x nh x batch-XCD).
// A: f32 -> float4 regs -> cvt -> swizzled ds_write bf16 (r5-proven, 0 conflicts),
//    2-buf. B: gloadlds 3-buf frag<64> (feat-proven, 0 conflicts).
// FIFO/step: issue [B(t+2):4, A(t+2):4] -> cmp(t) -> VMCNT(8) -> ds_write A(t+1)
// -> BARRIER. 64KB LDS -> 2 blk/CU.
__global__ __launch_bounds__(256) void gemm_adj_k(const float* __restrict__ adj,
                                                  const __bf16* __restrict__ ST,
                                                  __bf16* __restrict__ midT) {
  __shared__ alignas(16) __bf16 Aa[2][64 * 64];   // 8 KB x2
  __shared__ alignas(16) __bf16 Bs[3][128 * 64];  // 16 KB x3
  const int t = threadIdx.x;
  const int lane = t & 63, wave = t >> 6;
  const int l15 = lane & 15, l4 = lane >> 4;
  const int wr = (wave >> 1) * 32;   // wave row offset (2x2 waves, tile 32x64)
  const int wc = (wave & 1) * 64;    // wave col offset
  const int id = blockIdx.x;         // 512: bz=id&7 (XCD pin), nh=bit3, slab=id>>4
  const int bz = id & 7;
  const int nh = (id >> 3) & 1;
  const long long r0 = (long long)(id >> 4) * 64;
  const float* Ab = adj + (long long)bz * 4194304 + r0 * 2048;
  const __bf16* Bb = ST + (long long)bz * 524288 + (long long)nh * 128 * 2048;

  // A mapping: ci = c*256+t (c=0..3): row = ci>>4 (0..63), fq = ci&15 (float4 chunk)
  const int arow = t >> 4, afq = t & 15;  // c adds 16 to arow per step of 64... see loops
  // dest (bf16): granule g8 = fq>>1 swizzled by row&7, half = fq&1
  auto ldA = [&](int tile, float4 (&r)[4]) {
#pragma unroll
    for (int c = 0; c < 4; ++c)
      r[c] = *(const float4*)(Ab + (long long)(arow + c * 16) * 2048 + tile * 64 + afq * 4);
  };
  auto stA = [&](__bf16* dst, const float4 (&r)[4]) {
#pragma unroll
    for (int c = 0; c < 4; ++c) {
      const int row = arow + c * 16;
      const int off = row * 64 + (((afq >> 1) ^ (row & 7)) * 8) + (afq & 1) * 4;
      *(ushort4*)&dst[off] = f4_to_bf4(r[c]);
    }
  };

  f32x4 acc[2][4] = {};
  float4 rA[4], rB[4];

  auto cmp = [&](const __bf16* Ac, const __bf16* Bc) {
#pragma unroll
    for (int ks = 0; ks < 2; ++ks) {
      bf16x8 af[2], bf[4];
#pragma unroll
      for (int i = 0; i < 2; ++i) af[i] = frag<64>(Ac, wr + i * 16 + l15, ks * 4 + l4);
#pragma unroll
      for (int j = 0; j < 4; ++j) bf[j] = frag<64>(Bc, wc + j * 16 + l15, ks * 4 + l4);
      __builtin_amdgcn_s_setprio(1);
#pragma unroll
      for (int i = 0; i < 2; ++i)
#pragma unroll
        for (int j = 0; j < 4; ++j)
          acc[i][j] = __builtin_amdgcn_mfma_f32_16x16x32_bf16(af[i], bf[j], acc[i][j], 0, 0, 0);
      __builtin_amdgcn_s_setprio(0);
    }
  };

  // prologue: FIFO = [B0:4, A0:4, B1:4, A1:4]
  stage_bf16<128, 64, 256>(Bb, 2048, Bs[0], t);
  SCHEDB;
  ldA(0, rA);
  SCHEDB;
  stage_bf16<128, 64, 256>(Bb + 64, 2048, Bs[1], t);
  SCHEDB;
  ldA(1, rB);
  SCHEDB;
  VMCNT(8); SCHEDB;            // B0, A0 done; [B1:4, A1:4] in flight
  stA(Aa[0], rA);
  BARRIER;

  int curB = 0, stgB = 2;
#pragma unroll 1
  for (int tt = 0; tt < 30; tt += 2) {
    // even step: consume A(t+1)=rB, issue A(t+2)->rA, read Aa[0], write Aa[1]
    stage_bf16<128, 64, 256>(Bb + (tt + 2) * 64, 2048, Bs[stgB], t);
    SCHEDB;
    ldA(tt + 2, rA);
    SCHEDB;
    cmp(Aa[0], Bs[curB]);
    VMCNT(8); SCHEDB;          // retire B(t+1), A(t+1); keep (t+2) in flight
    stA(Aa[1], rB);
    BARRIER;
    curB = (curB == 2) ? 0 : curB + 1;
    stgB = (stgB == 2) ? 0 : stgB + 1;
    // odd step
    stage_bf16<128, 64, 256>(Bb + (tt + 3) * 64, 2048, Bs[stgB], t);
    SCHEDB;
    ldA(tt + 3, rB);
    SCHEDB;
    cmp(Aa[1], Bs[curB]);
    VMCNT(8); SCHEDB;
    stA(Aa[0], rA);
    BARRIER;
    curB = (curB == 2) ? 0 : curB + 1;
    stgB = (stgB == 2) ? 0 : stgB + 1;
  }
  // t=30 (even): in flight [B31:4, A31:4(rB)]
  cmp(Aa[0], Bs[curB]);
  VMCNT(0); SCHEDB;
  stA(Aa[1], rB);
  BARRIER;
  curB = (curB == 2) ? 0 : curB + 1;
  // t=31
  cmp(Aa[1], Bs[curB]);

  __bf16* Cb = midT + (long long)bz * 524288;
#pragma unroll
  for (int j = 0; j < 4; ++j) {
    const int l = nh * 128 + wc + j * 16 + l15;
#pragma unroll
    for (int i = 0; i < 2; ++i) {
      ushort4 u;
      u.x = f2bf(acc[i][j][0]); u.y = f2bf(acc[i][j][1]);
      u.z = f2bf(acc[i][j][2]); u.w = f2bf(acc[i][j][3]);
      *(ushort4*)(Cb + (long long)l * 2048 + r0 + wr + i * 16 + l4 * 4) = u;
    }
  }
}

// ---------------- G5: pfeat = ST @ xbT^T; triple-buffer counted-vmcnt (proven) -----
__global__ __launch_bounds__(256) void gemm_feat_k(const __bf16* __restrict__ ST,
                                                   const __bf16* __restrict__ xbT,
                                                   float* __restrict__ pfeat) {
  __shared__ alignas(16) __bf16 As[3][32 * 64];  // 12 KB
  __shared__ alignas(16) __bf16 Bs[3][64 * 64];  // 24 KB
  const int t = threadIdx.x;
  const int lane = t & 63, wave = t >> 6;
  const int l15 = lane & 15, l4 = lane >> 4;
  const int wn = wave * 16;
  const int id = blockIdx.x;   // 512: b=id&7 (XCD pin), kblk, fblk
  const int b = id & 7, j7 = id >> 3;
  const int kblk = j7 & 7, fblk = j7 >> 3;
  const __bf16* Ab = ST + (long long)b * 524288 + (long long)kblk * 32 * 2048;
  const __bf16* Bb = xbT + (long long)b * 1048576 + (long long)fblk * 64 * 2048;

  auto stage = [&](int s, int buf) {  // 3 gloadlds/thread
    stage_bf16<32, 64, 256>(Ab + s * 64, 2048, (__bf16*)As + buf * 2048, t);
    stage_bf16<64, 64, 256>(Bb + s * 64, 2048, (__bf16*)Bs + buf * 4096, t);
  };
  auto cmp = [&](int buf, f32x4 (&acc)[2]) {
    const __bf16* Ac = (const __bf16*)As + buf * 2048;
    const __bf16* Bc = (const __bf16*)Bs + buf * 4096;
#pragma unroll
    for (int ks = 0; ks < 2; ++ks) {
      bf16x8 af[2], bf;
#pragma unroll
      for (int i = 0; i < 2; ++i) af[i] = frag<64>(Ac, i * 16 + l15, ks * 4 + l4);
      bf = frag<64>(Bc, wn + l15, ks * 4 + l4);
#pragma unroll
      for (int i = 0; i < 2; ++i)
        acc[i] = __builtin_amdgcn_mfma_f32_16x16x32_bf16(af[i], bf, acc[i], 0, 0, 0);
    }
  };

  f32x4 acc[2] = {};
  stage(0, 0);
  SCHEDB;
  stage(1, 1);
  SCHEDB;
  VMCNT(3); SCHEDB;
  BARRIER;

  int cur = 0, stg = 2;
#pragma unroll 1
  for (int tt = 0; tt < 30; ++tt) {
    stage(tt + 2, stg);
    SCHEDB;
    cmp(cur, acc);
    VMCNT(3); SCHEDB;
    BARRIER;
    cur = (cur == 2) ? 0 : cur + 1;
    stg = (stg == 2) ? 0 : stg + 1;
  }
  cmp(cur, acc);
  VMCNT(0); SCHEDB;
  BARRIER;
  cur = (cur == 2) ? 0 : cur + 1;
  cmp(cur, acc);

  float* out = pfeat + (long long)b * 131072;
#pragma unroll
  for (int i = 0; i < 2; ++i)
#pragma unroll
    for (int r = 0; r < 4; ++r)
      out[(long long)(kblk * 32 + i * 16 + l4 * 4 + r) * 512 + fblk * 64 + wn + l15] =
          acc[i][r];
}

// ---------------- G4: pooled = ST @ midT^T; triple-buffer counted-vmcnt (proven) ---
__global__ __launch_bounds__(256) void gemm_pool_k(const __bf16* __restrict__ ST,
                                                   const __bf16* __restrict__ midT,
                                                   float* __restrict__ pooled) {
  __shared__ alignas(16) __bf16 As[3][32 * 64];
  __shared__ alignas(16) __bf16 Bs[3][32 * 64];
  const int t = threadIdx.x;
  const int lane = t & 63, wave = t >> 6;
  const int l15 = lane & 15, l4 = lane >> 4;
  const int wm = (wave >> 1) * 16, wn = (wave & 1) * 16;
  const int id = blockIdx.x;
  const int b = id & 7, j7 = id >> 3;
  const int kblk = j7 & 7, lblk = j7 >> 3;
  const __bf16* Ab = ST + (long long)b * 524288 + (long long)kblk * 32 * 2048;
  const __bf16* Bb = midT + (long long)b * 524288 + (long long)lblk * 32 * 2048;

  auto stage = [&](int s, int buf) {
    stage_bf16<32, 64, 256>(Ab + s * 64, 2048, (__bf16*)As + buf * 2048, t);
    stage_bf16<32, 64, 256>(Bb + s * 64, 2048, (__bf16*)Bs + buf * 2048, t);
  };
  auto cmp = [&](int buf, f32x4& acc) {
    const __bf16* Ac = (const __bf16*)As + buf * 2048;
    const __bf16* Bc = (const __bf16*)Bs + buf * 2048;
#pragma unroll
    for (int ks = 0; ks < 2; ++ks) {
      bf16x8 af = frag<64>(Ac, wm + l15, ks * 4 + l4);
      bf16x8 bf = frag<64>(Bc, wn + l15, ks * 4 + l4);
      acc = __builtin_amdgcn_mfma_f32_16x16x32_bf16(af, bf, acc, 0, 0, 0);
    }
  };

  f32x4 acc = {};
  stage(0, 0);
  SCHEDB;
  stage(1, 1);
  SCHEDB;
  VMCNT(2); SCHEDB;
  BARRIER;

  int cur = 0, stg = 2;
#pragma unroll 1
  for (int tt = 0; tt < 30; ++tt) {
    stage(tt + 2, stg);
    SCHEDB;
    cmp(cur, acc);
    VMCNT(2); SCHEDB;
    BARRIER;
    cur = (cur == 2) ? 0 : cur + 1;
    stg = (stg == 2) ? 0 : stg + 1;
  }
  cmp(cur, acc);
  VMCNT(0); SCHEDB;
  BARRIER;
  cur = (cur == 2) ? 0 : cur + 1;
  cmp(cur, acc);

  float* out = pooled + (long long)b * 65536;
#pragma unroll
  for (int r = 0; r < 4; ++r)
    out[(long long)(kblk * 32 + wm + l4 * 4 + r) * 256 + lblk * 32 + wn + l15] = acc[r];
}

// ---------------- rowsum -> dinv; finalize ----------------
__global__ __launch_bounds__(256) void rowsum_k(const float* __restrict__ pooled,
                                                float* __restrict__ dinv) {
  const int gr = blockIdx.x * 4 + (threadIdx.x >> 6);
  const int lane = threadIdx.x & 63;
  const float* p = pooled + (long long)gr * 256;
  float s = p[lane] + p[lane + 64] + p[lane + 128] + p[lane + 192];
#pragma unroll
  for (int o = 32; o > 0; o >>= 1) s += __shfl_xor(s, o, 64);
  if (lane == 0) dinv[gr] = rsqrtf(s + 1e-9f);
}

__global__ __launch_bounds__(256) void finalize_k(const float* __restrict__ pooled,
                                                  const float* __restrict__ dinv,
                                                  float* __restrict__ outAdj,
                                                  float* __restrict__ pmask) {
  const long long i = blockIdx.x * 256LL + threadIdx.x;
  const int c = (int)(i & 255);
  const int r = (int)((i >> 8) & 255);
  const int b = (int)(i >> 16);
  outAdj[i] = pooled[i] * dinv[b * 256 + r] * dinv[b * 256 + c];
  if (i < 2048) pmask[i] = 1.0f;
}

extern "C" void kernel_launch(void* const* d_in, const int* in_sizes, int n_in,
                              void* d_out, int out_size, void* d_ws, size_t ws_size,
                              hipStream_t stream) {
  (void)in_sizes; (void)n_in; (void)out_size; (void)ws_size;
  const float* x    = (const float*)d_in[0];  // [8,2048,512]
  const float* adj  = (const float*)d_in[1];  // [8,2048,2048]
  const float* mask = (const float*)d_in[2];  // [8,2048]
  const float* W1   = (const float*)d_in[3];  // [512,256]
  const float* b1   = (const float*)d_in[4];  // [256]
  const float* W2   = (const float*)d_in[5];  // [256,256]
  const float* b2   = (const float*)d_in[6];  // [256]

  char* ws = (char*)d_ws;  // total 36,052,992 B (~34.4 MiB)
  __bf16* ST     = (__bf16*)(ws + 0);          //  8,388,608  [8][256][2048]
  __bf16* midT   = (__bf16*)(ws + 8388608);    //  8,388,608  [8][256][2048]
  __bf16* xbT    = (__bf16*)(ws + 16777216);   // 16,777,216  [8][512][2048]
  float*  pooled = (float*)(ws + 33554432);    //  2,097,152  [8][256][256]
  float*  dinv   = (float*)(ws + 35651584);    //      8,192  [8][256]
  __bf16* W1T    = (__bf16*)(ws + 35659776);   //    262,144  [256][512]
  __bf16* W2T    = (__bf16*)(ws + 35921920);   //    131,072  [256][256]

  float* pfeat  = (float*)d_out;               // [8,256,512]
  float* outAdj = (float*)d_out + 1048576;     // [8,256,256]
  float* pmask  = (float*)d_out + 1572864;     // [8,256]

  prep_k<<<2096, 256, 0, stream>>>(x, W1, W2, xbT, W1T, W2T);
  assign_fused_k<<<512, 256, 0, stream>>>(x, W1T, W2T, b1, b2, mask, ST);
  gemm_feat_k<<<512, 256, 0, stream>>>(ST, xbT, pfeat);
  gemm_adj_k<<<512, 256, 0, stream>>>(adj, ST, midT);
  gemm_pool_k<<<512, 256, 0, stream>>>(ST, midT, pooled);
  rowsum_k<<<512, 256, 0, stream>>>(pooled, dinv);
  finalize_k<<<2048, 256, 0, stream>>>(pooled, dinv, outAdj, pmask);
}